// Round 14
// baseline (160.477 us; speedup 1.0000x reference)
//
#include <hip/hip_runtime.h>
#include <math.h>

// Problem constants
#define F_ 126
#define NPG 128              // nodes per graph
#define EPG 2048             // edges per graph
#define ET 524288            // total edges
#define NEG_SLOPE 0.2f

typedef short bf16x8 __attribute__((ext_vector_type(8)));
typedef float f32x4 __attribute__((ext_vector_type(4)));

__device__ __forceinline__ float bf2f(unsigned short u) {
  return __uint_as_float(((unsigned)u) << 16);
}
__device__ __forceinline__ unsigned short f2bf(float f) {
  unsigned x = __float_as_uint(f);
  unsigned r = x + 0x7fffu + ((x >> 16) & 1u);   // RNE
  return (unsigned short)(r >> 16);
}
// single-instruction packed f32x2 -> bf16x2 (RNE), gfx950
__device__ __forceinline__ unsigned cvtpk(float lo, float hi) {
  unsigned r;
  asm("v_cvt_pk_bf16_f32 %0, %1, %2" : "=v"(r) : "v"(lo), "v"(hi));
  return r;
}
union bfpack { unsigned u[4]; bf16x8 v; };

#define SW(r)  (((r) & 7) << 4)    // bf16-row swizzle (16B granule)
#define SWB(d) (((d) & 15) << 3)   // byte-matrix swizzle (8B granule)

// ws layout (bytes):
//   [0, 393216)                wct bf16 [3][256][256]
//   [393216, +4MB)             M u8 [256 g][16384]  (SWB-swizzled)
//   [4587520, +2MB)            tab f32 [256 g][4 tbl][4 hd][128]  (Es,Fs,Ed,Fd)
//   [6684672, +16MB)           hT bf16 [256 g][256 dim][128 src]
#define WS_M    393216
#define WS_TAB  4587520
#define WS_HT   6684672

// ---------------- K0P: wct (coalesced) + M multiplicity build + out zero ------------------
__global__ __launch_bounds__(256) void k0p(
    const float* __restrict__ Wf, const float* __restrict__ Wu,
    const float* __restrict__ Wi, const float* __restrict__ Wg,
    const int* __restrict__ ei,
    unsigned short* __restrict__ wct, unsigned char* __restrict__ Mws,
    float* __restrict__ out) {
  const int blk = blockIdx.x;
  const int tid = threadIdx.x;
  if (blk < 96) {
    const int type = blk / 32;
    const int kc = blk % 32;
    const float* Wx = (type == 0) ? Wf : ((type == 1) ? Wu : Wi);
    __shared__ float Xs[8][256];
#pragma unroll
    for (int r = 0; r < 8; ++r) Xs[r][tid] = Wx[(kc * 8 + r) * 256 + tid];  // coalesced
    __syncthreads();
    float acc[8] = {};
#pragma unroll 16
    for (int j = 0; j < 256; ++j) {
      float wg = Wg[j * 256 + tid];                // coalesced across threads
#pragma unroll
      for (int r = 0; r < 8; ++r) acc[r] += Xs[r][j] * wg;
    }
#pragma unroll
    for (int r = 0; r < 8; ++r)
      wct[((size_t)type * 256 + tid) * 256 + kc * 8 + r] = f2bf(acc[r]);
  } else {
    // per-graph M build (byte-packed multiplicity, SWB-swizzled) + out zero
    const int g = blk - 96;
    if (tid < F_) out[(size_t)g * F_ + tid] = 0.f;
    __shared__ __align__(16) unsigned char Ml[16384];
    {
      uint4 z = { 0, 0, 0, 0 };
#pragma unroll
      for (int i = 0; i < 4; ++i) *(uint4*)(Ml + tid * 16 + i * 4096) = z;
    }
    int4 sa = *(const int4*)(ei + (size_t)g * EPG + tid * 8);
    int4 sb = *(const int4*)(ei + (size_t)g * EPG + tid * 8 + 4);
    int4 da = *(const int4*)(ei + (size_t)ET + (size_t)g * EPG + tid * 8);
    int4 db = *(const int4*)(ei + (size_t)ET + (size_t)g * EPG + tid * 8 + 4);
    __syncthreads();
    int ss[8] = { sa.x - g * NPG, sa.y - g * NPG, sa.z - g * NPG, sa.w - g * NPG,
                  sb.x - g * NPG, sb.y - g * NPG, sb.z - g * NPG, sb.w - g * NPG };
    int dd[8] = { da.x - g * NPG, da.y - g * NPG, da.z - g * NPG, da.w - g * NPG,
                  db.x - g * NPG, db.y - g * NPG, db.z - g * NPG, db.w - g * NPG };
#pragma unroll
    for (int j = 0; j < 8; ++j) {
      int bofs = (dd[j] * 128 + ss[j]) ^ SWB(dd[j]);
      atomicAdd((int*)(Ml + (bofs & ~3)), 1 << ((bofs & 3) * 8));
    }
    __syncthreads();
    unsigned char* Mdst = Mws + (size_t)g * 16384;
#pragma unroll
    for (int i = 0; i < 4; ++i)
      *(uint4*)(Mdst + tid * 16 + i * 4096) = *(const uint4*)(Ml + tid * 16 + i * 4096);
  }
}

// ---------------- K1G: gather-GEMM1, max-TLP, barrier-free --------------------------------
// 2048 blocks = (g, rowoct 0..7); 256 thr = 4 waves; wave = 16 rows x 64 dims (head = wv).
// as/ad complete per wave; exp tables + hT transpose written direct to ws; GEMV in rowoct 7.
__global__ __launch_bounds__(256) void k1g(
    const int* __restrict__ fid, const int* __restrict__ userid, const int* __restrict__ itemid,
    const float* __restrict__ ftab, const float* __restrict__ utab, const float* __restrict__ itab,
    const unsigned short* __restrict__ wct,
    const float* __restrict__ a_src, const float* __restrict__ a_dst,
    float* __restrict__ tabws, unsigned short* __restrict__ hTws) {
  const int g = blockIdx.x >> 3;
  const int rowoct = blockIdx.x & 7;
  const int tid = threadIdx.x;
  const int lane = tid & 63;
  const int wv = tid >> 6;           // 0..3 == head index
  const int rl = lane & 15;
  const int kg = lane >> 4;

  const int arow = rowoct * 16 + rl;
  const float* rp;
  if (arow < F_)       rp = ftab + (size_t)fid[g * F_ + arow] * 256;
  else if (arow == F_) rp = utab + (size_t)userid[g] * 256;  // placeholder; GEMV overwrites
  else                 rp = itab + (size_t)itemid[g] * 256;
  const unsigned short* bp[4];
#pragma unroll
  for (int nf = 0; nf < 4; ++nf)
    bp[nf] = wct + (size_t)(wv * 64 + nf * 16 + rl) * 256;

  f32x4 acc[4] = {};
#pragma unroll
  for (int ks = 0; ks < 8; ++ks) {
    float4 v0 = *(const float4*)(rp + ks * 32 + kg * 8);
    float4 v1 = *(const float4*)(rp + ks * 32 + kg * 8 + 4);
    bfpack p;
    p.u[0] = cvtpk(v0.x, v0.y); p.u[1] = cvtpk(v0.z, v0.w);
    p.u[2] = cvtpk(v1.x, v1.y); p.u[3] = cvtpk(v1.z, v1.w);
#pragma unroll
    for (int nf = 0; nf < 4; ++nf) {
      bf16x8 bfv = *(const bf16x8*)(bp[nf] + ks * 32 + kg * 8);
      acc[nf] = __builtin_amdgcn_mfma_f32_16x16x32_bf16(p.v, bfv, acc[nf], 0, 0, 0);
    }
  }

  // exp tables (head = wv) from f32 acc
  {
    float asv[4], adv[4];
#pragma unroll
    for (int nf = 0; nf < 4; ++nf) {
      asv[nf] = a_src[wv * 64 + nf * 16 + rl];
      adv[nf] = a_dst[wv * 64 + nf * 16 + rl];
    }
    float* tb = tabws + (size_t)g * 2048;
#pragma unroll
    for (int i = 0; i < 4; ++i) {
      float ps = 0.f, pd = 0.f;
#pragma unroll
      for (int nf = 0; nf < 4; ++nf) { ps += acc[nf][i] * asv[nf]; pd += acc[nf][i] * adv[nf]; }
#pragma unroll
      for (int d2 = 1; d2 < 16; d2 <<= 1) { ps += __shfl_xor(ps, d2); pd += __shfl_xor(pd, d2); }
      int row = rowoct * 16 + kg * 4 + i;
      if (rl == 0 && row < F_) {
        tb[0 * 512 + wv * 128 + row] = __expf(ps);
        tb[1 * 512 + wv * 128 + row] = __expf(NEG_SLOPE * ps);
        tb[2 * 512 + wv * 128 + row] = __expf(pd);
        tb[3 * 512 + wv * 128 + row] = __expf(NEG_SLOPE * pd);
      }
    }
  }

  // transpose-write hT[dim][src] (src 126/127 via GEMV below)
  {
    unsigned short* hT = hTws + (size_t)g * 32768;
    const int srcb = rowoct * 16 + kg * 4;
#pragma unroll
    for (int nf = 0; nf < 4; ++nf) {
      int dim = wv * 64 + nf * 16 + rl;
      unsigned lo = cvtpk(acc[nf][0], acc[nf][1]);
      unsigned hi = cvtpk(acc[nf][2], acc[nf][3]);
      if (srcb < 124) { uint2 u = { lo, hi }; *(uint2*)(hT + (size_t)dim * 128 + srcb) = u; }
      else            { *(unsigned*)(hT + (size_t)dim * 128 + srcb) = lo; }  // rows 124,125
    }
  }

  // GEMV for user/item source rows (rowoct==7 blocks only)
  // thread -> (r2 = 126 + (tid>>7), dims dml and dml+128); wave wv covers heads (wv&1), (wv&1)+2
  if (rowoct == 7) {
    const int r2 = 126 + (tid >> 7);
    const int dml = tid & 127;
    const float* er = (tid < 128) ? (utab + (size_t)userid[g] * 256)
                                  : (itab + (size_t)itemid[g] * 256);
    const int type = 1 + (tid >> 7);
    const uint4* w0 = (const uint4*)(wct + ((size_t)type * 256 + dml) * 256);
    const uint4* w1 = (const uint4*)(wct + ((size_t)type * 256 + 128 + dml) * 256);
    const float4* e4 = (const float4*)er;
    float hv0 = 0.f, hv1 = 0.f;
#pragma unroll 4
    for (int j = 0; j < 32; ++j) {
      uint4 wa = w0[j], wb = w1[j];
      float4 e0 = e4[2 * j], e1 = e4[2 * j + 1];
      const unsigned short* pa = (const unsigned short*)&wa;
      const unsigned short* pb = (const unsigned short*)&wb;
      hv0 += e0.x * bf2f(pa[0]) + e0.y * bf2f(pa[1]) + e0.z * bf2f(pa[2]) + e0.w * bf2f(pa[3]);
      hv0 += e1.x * bf2f(pa[4]) + e1.y * bf2f(pa[5]) + e1.z * bf2f(pa[6]) + e1.w * bf2f(pa[7]);
      hv1 += e0.x * bf2f(pb[0]) + e0.y * bf2f(pb[1]) + e0.z * bf2f(pb[2]) + e0.w * bf2f(pb[3]);
      hv1 += e1.x * bf2f(pb[4]) + e1.y * bf2f(pb[5]) + e1.z * bf2f(pb[6]) + e1.w * bf2f(pb[7]);
    }
    float gps0 = hv0 * a_src[dml],       gpd0 = hv0 * a_dst[dml];
    float gps1 = hv1 * a_src[128 + dml], gpd1 = hv1 * a_dst[128 + dml];
#pragma unroll
    for (int d2 = 32; d2 >= 1; d2 >>= 1) {
      gps0 += __shfl_xor(gps0, d2); gpd0 += __shfl_xor(gpd0, d2);
      gps1 += __shfl_xor(gps1, d2); gpd1 += __shfl_xor(gpd1, d2);
    }
    float* tb = tabws + (size_t)g * 2048;
    if (lane == 0) {
      int hA = wv & 1, hB = hA + 2;
      tb[0 * 512 + hA * 128 + r2] = __expf(gps0);
      tb[1 * 512 + hA * 128 + r2] = __expf(NEG_SLOPE * gps0);
      tb[2 * 512 + hA * 128 + r2] = __expf(gpd0);
      tb[3 * 512 + hA * 128 + r2] = __expf(NEG_SLOPE * gpd0);
      tb[0 * 512 + hB * 128 + r2] = __expf(gps1);
      tb[1 * 512 + hB * 128 + r2] = __expf(NEG_SLOPE * gps1);
      tb[2 * 512 + hB * 128 + r2] = __expf(gpd1);
      tb[3 * 512 + hB * 128 + r2] = __expf(NEG_SLOPE * gpd1);
    }
    unsigned short* hT = hTws + (size_t)g * 32768;
    hT[(size_t)dml * 128 + r2] = f2bf(hv0);
    hT[(size_t)(128 + dml) * 128 + r2] = f2bf(hv1);
  }
}

// ---------------- K3: per-(graph, head) GEMM2 + fused epilogue ----------------------------
// 1024 blocks = (g, hd); 256 threads, 4 waves; 4 blocks/CU (LDS ~35 KB).
__global__ __launch_bounds__(256, 4) void k3(
    const unsigned char* __restrict__ Mws, const unsigned short* __restrict__ hTws,
    const float* __restrict__ tabws,
    const float* __restrict__ W_out, const float* __restrict__ b_out,
    float* __restrict__ out) {
  const int g = blockIdx.x & 255;
  const int hd = blockIdx.x >> 8;
  const int tid = threadIdx.x;
  const int lane = tid & 63;
  const int wid = tid >> 6;            // 0..3
  const int rl = lane & 15;
  const int kg = lane >> 4;

  __shared__ __align__(16) unsigned char Ml[16384];
  __shared__ __align__(16) unsigned short Htl[8192];   // [64 dim][128 src], SW-swizzled
  __shared__ float Es[128], Fs[128], Ed[128], Fd[128], wol[64], lpf[128];

  // stage M (linear; SWB baked at build)
  const unsigned char* Msrc = Mws + (size_t)g * 16384;
#pragma unroll
  for (int i = 0; i < 4; ++i)
    *(uint4*)(Ml + tid * 16 + i * 4096) = *(const uint4*)(Msrc + tid * 16 + i * 4096);
  // stage hT head slice with SW swizzle
  const char* hsrc = (const char*)(hTws + (size_t)g * 32768 + (size_t)hd * 8192);
#pragma unroll
  for (int i = 0; i < 4; ++i) {
    int idx = tid + i * 256;           // 16B granule, 1024 total
    int off = idx * 16;
    int dim = idx >> 4;
    uint4 v = *(const uint4*)(hsrc + off);
    *(uint4*)((char*)Htl + (off ^ SW(dim))) = v;
  }
  // stage tables (4 x 128 floats)
  {
    const float* tsrc = tabws + (size_t)g * 2048 + hd * 128;
#pragma unroll
    for (int k = 0; k < 2; ++k) {
      int f = tid * 2 + k;             // 0..511
      int tbl = f >> 7, node = f & 127;
      float v = tsrc[tbl * 512 + node];
      float* dstp = (tbl == 0) ? Es : ((tbl == 1) ? Fs : ((tbl == 2) ? Ed : Fd));
      dstp[node] = v;
    }
  }
  if (tid < 64) wol[tid] = W_out[hd * 64 + tid];
  const float bo = b_out[0];
  __syncthreads();

  const int m2 = wid * 32;
  const float Edv0 = Ed[m2 + rl],      Fdv0 = Fd[m2 + rl];
  const float Edv1 = Ed[m2 + 16 + rl], Fdv1 = Fd[m2 + 16 + rl];
  float denp0 = 0.f, denp1 = 0.f;
  f32x4 acc2[2][4] = {};

#pragma unroll
  for (int ks = 0; ks < 4; ++ks) {
    f32x4 Es0 = *(const f32x4*)(&Es[ks * 32 + kg * 8]);
    f32x4 Es1 = *(const f32x4*)(&Es[ks * 32 + kg * 8 + 4]);
    f32x4 Fs0 = *(const f32x4*)(&Fs[ks * 32 + kg * 8]);
    f32x4 Fs1 = *(const f32x4*)(&Fs[ks * 32 + kg * 8 + 4]);
    bf16x8 b2[4];
#pragma unroll
    for (int nf = 0; nf < 4; ++nf) {
      int dim = nf * 16 + rl;
      b2[nf] = *(const bf16x8*)((const char*)Htl + ((dim * 256 + ks * 64 + kg * 16) ^ SW(dim)));
    }
#pragma unroll
    for (int mf = 0; mf < 2; ++mf) {
      int d = m2 + mf * 16 + rl;
      uint2 m8 = *(const uint2*)(Ml + ((d * 128 + ks * 32 + kg * 8) ^ SWB(d)));
      float Edv = mf ? Edv1 : Edv0, Fdv = mf ? Fdv1 : Fdv0;
      float av[8], dsum = 0.f;
#pragma unroll
      for (int j = 0; j < 8; ++j) {
        float mv = (float)(int)((j < 4 ? (m8.x >> (8 * j)) : (m8.y >> (8 * (j - 4)))) & 255u);
        float w = fmaxf(((j < 4) ? Es0[j] : Es1[j - 4]) * Edv,
                        ((j < 4) ? Fs0[j] : Fs1[j - 4]) * Fdv) * mv;
        av[j] = w; dsum += w;
      }
      if (mf) denp1 += dsum; else denp0 += dsum;
      bfpack a2;
      a2.u[0] = cvtpk(av[0], av[1]); a2.u[1] = cvtpk(av[2], av[3]);
      a2.u[2] = cvtpk(av[4], av[5]); a2.u[3] = cvtpk(av[6], av[7]);
#pragma unroll
      for (int nf = 0; nf < 4; ++nf)
        acc2[mf][nf] = __builtin_amdgcn_mfma_f32_16x16x32_bf16(a2.v, b2[nf], acc2[mf][nf], 0, 0, 0);
    }
  }
  denp0 += __shfl_xor(denp0, 16); denp0 += __shfl_xor(denp0, 32);
  denp1 += __shfl_xor(denp1, 16); denp1 += __shfl_xor(denp1, 32);

  float lp[2][4] = {};
#pragma unroll
  for (int mf = 0; mf < 2; ++mf) {
#pragma unroll
    for (int i = 0; i < 4; ++i) {
      float dni = __shfl(mf ? denp1 : denp0, kg * 4 + i);
      float rd = __builtin_amdgcn_rcpf(dni + 1e-16f);
#pragma unroll
      for (int nf = 0; nf < 4; ++nf) {
        float v = acc2[mf][nf][i] * rd;
        v = (v > 0.f) ? v : (__expf(v) - 1.f);
        lp[mf][i] += v * wol[nf * 16 + rl];
      }
    }
  }
#pragma unroll
  for (int mf = 0; mf < 2; ++mf) {
#pragma unroll
    for (int i = 0; i < 4; ++i) {
      float v = lp[mf][i];
#pragma unroll
      for (int d2 = 1; d2 < 16; d2 <<= 1) v += __shfl_xor(v, d2);
      if (rl == 0) lpf[m2 + mf * 16 + kg * 4 + i] = v;
    }
  }
  __syncthreads();
  if (tid < F_) atomicAdd(&out[(size_t)g * F_ + tid], lpf[tid] + (hd == 0 ? bo : 0.f));
}

extern "C" void kernel_launch(void* const* d_in, const int* in_sizes, int n_in,
                              void* d_out, int out_size, void* d_ws, size_t ws_size,
                              hipStream_t stream) {
  const int* fid      = (const int*)d_in[0];
  const int* userid   = (const int*)d_in[1];
  const int* itemid   = (const int*)d_in[2];
  const int* ei       = (const int*)d_in[3];
  const float* ftab   = (const float*)d_in[4];
  const float* utab   = (const float*)d_in[5];
  const float* itab   = (const float*)d_in[6];
  const float* Wf     = (const float*)d_in[7];
  const float* Wu     = (const float*)d_in[8];
  const float* Wi     = (const float*)d_in[9];
  const float* Wg     = (const float*)d_in[10];
  const float* a_src  = (const float*)d_in[11];
  const float* a_dst  = (const float*)d_in[12];
  const float* W_out  = (const float*)d_in[13];
  const float* b_out  = (const float*)d_in[14];
  float* out = (float*)d_out;

  unsigned short* ws_wct = (unsigned short*)d_ws;
  unsigned char*  ws_M   = (unsigned char*)d_ws + WS_M;
  float*          ws_tab = (float*)((char*)d_ws + WS_TAB);
  unsigned short* ws_hT  = (unsigned short*)((char*)d_ws + WS_HT);

  hipLaunchKernelGGL(k0p, dim3(352), dim3(256), 0, stream,
                     Wf, Wu, Wi, Wg, ei, ws_wct, ws_M, out);
  hipLaunchKernelGGL(k1g, dim3(2048), dim3(256), 0, stream,
                     fid, userid, itemid, ftab, utab, itab, ws_wct,
                     a_src, a_dst, ws_tab, ws_hT);
  hipLaunchKernelGGL(k3, dim3(1024), dim3(256), 0, stream,
                     ws_M, ws_hT, ws_tab, W_out, b_out, out);
}

// Round 16
// 66.277 us; speedup vs baseline: 2.4213x; 2.4213x over previous
//
#include <hip/hip_runtime.h>
#include <math.h>

// Problem constants
#define F_ 126
#define NPG 128              // nodes per graph
#define EPG 2048             // edges per graph
#define ET 524288            // total edges
#define NEG_SLOPE 0.2f

typedef short bf16x8 __attribute__((ext_vector_type(8)));
typedef float f32x4 __attribute__((ext_vector_type(4)));

__device__ __forceinline__ float bf2f(unsigned short u) {
  return __uint_as_float(((unsigned)u) << 16);
}
__device__ __forceinline__ unsigned short f2bf(float f) {
  unsigned x = __float_as_uint(f);
  unsigned r = x + 0x7fffu + ((x >> 16) & 1u);   // RNE
  return (unsigned short)(r >> 16);
}
// single-instruction packed f32x2 -> bf16x2 (RNE), gfx950
__device__ __forceinline__ unsigned cvtpk(float lo, float hi) {
  unsigned r;
  asm("v_cvt_pk_bf16_f32 %0, %1, %2" : "=v"(r) : "v"(lo), "v"(hi));
  return r;
}
union bfpack { unsigned u[4]; bf16x8 v; };

#define SW(r)  (((r) & 7) << 4)    // bf16-row swizzle (16B granule)
#define SWB(d) (((d) & 15) << 3)   // byte-matrix swizzle (8B granule)

// ws layout: [0,384K) wct bf16 [3][256][256];  [WS_M, +4MB) M u8 [256 g][16384] (SWB)
#define WS_M    393216

// ---------------- K0P: wct (coalesced) + M multiplicity build -----------------------------
__global__ __launch_bounds__(256) void k0p(
    const float* __restrict__ Wf, const float* __restrict__ Wu,
    const float* __restrict__ Wi, const float* __restrict__ Wg,
    const int* __restrict__ ei,
    unsigned short* __restrict__ wct, unsigned char* __restrict__ Mws) {
  const int blk = blockIdx.x;
  const int tid = threadIdx.x;
  if (blk < 96) {
    const int type = blk / 32;
    const int kc = blk % 32;
    const float* Wx = (type == 0) ? Wf : ((type == 1) ? Wu : Wi);
    __shared__ float Xs[8][256];
#pragma unroll
    for (int r = 0; r < 8; ++r) Xs[r][tid] = Wx[(kc * 8 + r) * 256 + tid];  // coalesced
    __syncthreads();
    float acc[8] = {};
#pragma unroll 16
    for (int j = 0; j < 256; ++j) {
      float wg = Wg[j * 256 + tid];                // coalesced across threads
#pragma unroll
      for (int r = 0; r < 8; ++r) acc[r] += Xs[r][j] * wg;
    }
#pragma unroll
    for (int r = 0; r < 8; ++r)
      wct[((size_t)type * 256 + tid) * 256 + kc * 8 + r] = f2bf(acc[r]);
  } else {
    // per-graph M build (byte-packed multiplicity, SWB-swizzled)
    const int g = blk - 96;
    __shared__ __align__(16) unsigned char Ml[16384];
    {
      uint4 z = { 0, 0, 0, 0 };
#pragma unroll
      for (int i = 0; i < 4; ++i) *(uint4*)(Ml + tid * 16 + i * 4096) = z;
    }
    int4 sa = *(const int4*)(ei + (size_t)g * EPG + tid * 8);
    int4 sb = *(const int4*)(ei + (size_t)g * EPG + tid * 8 + 4);
    int4 da = *(const int4*)(ei + (size_t)ET + (size_t)g * EPG + tid * 8);
    int4 db = *(const int4*)(ei + (size_t)ET + (size_t)g * EPG + tid * 8 + 4);
    __syncthreads();
    int ss[8] = { sa.x - g * NPG, sa.y - g * NPG, sa.z - g * NPG, sa.w - g * NPG,
                  sb.x - g * NPG, sb.y - g * NPG, sb.z - g * NPG, sb.w - g * NPG };
    int dd[8] = { da.x - g * NPG, da.y - g * NPG, da.z - g * NPG, da.w - g * NPG,
                  db.x - g * NPG, db.y - g * NPG, db.z - g * NPG, db.w - g * NPG };
#pragma unroll
    for (int j = 0; j < 8; ++j) {
      int bofs = (dd[j] * 128 + ss[j]) ^ SWB(dd[j]);
      atomicAdd((int*)(Ml + (bofs & ~3)), 1 << ((bofs & 3) * 8));
    }
    __syncthreads();
    unsigned char* Mdst = Mws + (size_t)g * 16384;
#pragma unroll
    for (int i = 0; i < 4; ++i)
      *(uint4*)(Mdst + tid * 16 + i * 4096) = *(const uint4*)(Ml + tid * 16 + i * 4096);
  }
}

// ---------------- K2F: fused per-graph kernel; A reg-staged to LDS ------------------------
// LDS: [0,64K) A-stage bf16 [128 rows][512B] (XOR-swz) -> hT bf16 [256][256B] after GEMM1
//      [64K,+16K) M u8 | [+8K) exp tables Es/Fs/Ed/Fd | asl/adl/wo/lpf
#define OFF_A    0
#define OFF_HT   0
#define OFF_M    65536
#define OFF_ES   81920
#define OFF_FS   83968
#define OFF_ED   86016
#define OFF_FD   88064
#define OFF_ASL  90112
#define OFF_ADL  91136
#define OFF_WO   92160
#define OFF_LP   93184
#define LDS_SZ   94208

__global__ __launch_bounds__(1024, 1) void k2f(
    const int* __restrict__ fid, const int* __restrict__ userid, const int* __restrict__ itemid,
    const float* __restrict__ ftab, const float* __restrict__ utab, const float* __restrict__ itab,
    const unsigned short* __restrict__ wct, const unsigned char* __restrict__ Mws,
    const float* __restrict__ a_src, const float* __restrict__ a_dst,
    const float* __restrict__ W_out, const float* __restrict__ b_out,
    float* __restrict__ out) {
  __shared__ __align__(16) char smem[LDS_SZ];
  const int g = blockIdx.x;
  const int tid = threadIdx.x;
  const int lane = tid & 63;
  const int wid = tid >> 6;          // 0..15
  const int rl = lane & 15;
  const int kg = lane >> 4;

  char* Ht = smem + OFF_HT;
  char* Mb = smem + OFF_M;
  float* EsT = (float*)(smem + OFF_ES);   // [hd*128 + node]
  float* FsT = (float*)(smem + OFF_FS);
  float* EdT = (float*)(smem + OFF_ED);
  float* FdT = (float*)(smem + OFF_FD);
  float* asl = (float*)(smem + OFF_ASL);
  float* adl = (float*)(smem + OFF_ADL);
  float* wo  = (float*)(smem + OFF_WO);
  float* lpf = (float*)(smem + OFF_LP);

  // M: global -> LDS (own region, written once, read after b1)
  *(uint4*)(Mb + tid * 16) = *(const uint4*)(Mws + (size_t)g * 16384 + tid * 16);

  if (tid < 256)      { asl[tid] = a_src[tid]; wo[tid] = W_out[tid]; }
  else if (tid < 512) { adl[tid - 256] = a_dst[tid - 256]; }
  const float bo = b_out[0];

  // ---- A-stage: gather embed rows -> bf16 LDS [128][512B], XOR-swizzled ----
  // thread t: row r = t>>3, q = t&7. Instr j: float4 at floats q*4 + j*32
  // (lanes q=0..7 cover 128B contiguous per row per instruction -> minimal segments).
  {
    const int r = tid >> 3, q = tid & 7;
    const float* srcrow;
    if (r < F_)       srcrow = ftab + (size_t)fid[g * F_ + r] * 256;
    else if (r == F_) srcrow = utab + (size_t)userid[g] * 256;  // placeholder; rows 126/127 fixed by GEMV
    else              srcrow = itab + (size_t)itemid[g] * 256;
    char* Ab = smem + OFF_A;
#pragma unroll
    for (int j = 0; j < 8; ++j) {
      float4 v = *(const float4*)(srcrow + q * 4 + j * 32);
      uint2 st;
      st.x = cvtpk(v.x, v.y);
      st.y = cvtpk(v.z, v.w);
      *(uint2*)(Ab + r * 512 + ((q * 8 + j * 64) ^ SW(r))) = st;
    }
  }
  __syncthreads();                                           // b0: A staged, M/asl/adl ready

  // ---- GEMM1: h = emb @ Wc(type0); A from LDS, B direct from L2 (R10 pattern) ----
  const int mh = wid & 3, nq = wid >> 2;    // rows mh*32..+32, dims nq*64..+64 (head nq)
  const unsigned short* bp[4];
#pragma unroll
  for (int nf = 0; nf < 4; ++nf)
    bp[nf] = wct + (size_t)(nq * 64 + nf * 16 + rl) * 256;

  f32x4 acc[2][4] = {};
  {
    const char* Ab = smem + OFF_A;
#pragma unroll
    for (int ks = 0; ks < 8; ++ks) {
      bf16x8 af[2], bfv[4];
#pragma unroll
      for (int mf = 0; mf < 2; ++mf) {
        int row = mh * 32 + mf * 16 + rl;
        af[mf] = *(const bf16x8*)(Ab + row * 512 + ((ks * 64 + kg * 16) ^ SW(row)));
      }
#pragma unroll
      for (int nf = 0; nf < 4; ++nf)
        bfv[nf] = *(const bf16x8*)(bp[nf] + ks * 32 + kg * 8);
#pragma unroll
      for (int mf = 0; mf < 2; ++mf)
#pragma unroll
        for (int nf = 0; nf < 4; ++nf)
          acc[mf][nf] = __builtin_amdgcn_mfma_f32_16x16x32_bf16(af[mf], bfv[nf], acc[mf][nf], 0, 0, 0);
    }
  }

  // ---- exp tables from f32 acc (head = nq) ----
  {
    float asv[4], adv[4];
#pragma unroll
    for (int nf = 0; nf < 4; ++nf) {
      asv[nf] = asl[nq * 64 + nf * 16 + rl];
      adv[nf] = adl[nq * 64 + nf * 16 + rl];
    }
#pragma unroll
    for (int mf = 0; mf < 2; ++mf) {
#pragma unroll
      for (int i = 0; i < 4; ++i) {
        float ps = 0.f, pd = 0.f;
#pragma unroll
        for (int nf = 0; nf < 4; ++nf) { float v = acc[mf][nf][i]; ps += v * asv[nf]; pd += v * adv[nf]; }
#pragma unroll
        for (int d2 = 1; d2 < 16; d2 <<= 1) { ps += __shfl_xor(ps, d2); pd += __shfl_xor(pd, d2); }
        int row = mh * 32 + mf * 16 + kg * 4 + i;
        if (rl == 0 && row < F_) {
          EsT[nq * 128 + row] = __expf(ps);
          FsT[nq * 128 + row] = __expf(NEG_SLOPE * ps);
          EdT[nq * 128 + row] = __expf(pd);
          FdT[nq * 128 + row] = __expf(NEG_SLOPE * pd);
        }
      }
    }
  }
  __syncthreads();                         // A-stage reads done -> region reusable for hT

  // ---- transpose-write hT[dim][src] into freed A region ----
  {
#pragma unroll
    for (int mf = 0; mf < 2; ++mf) {
      int srcb = mh * 32 + mf * 16 + kg * 4;
#pragma unroll
      for (int nf = 0; nf < 4; ++nf) {
        int dim = nq * 64 + nf * 16 + rl;
        unsigned lo = cvtpk(acc[mf][nf][0], acc[mf][nf][1]);
        unsigned hi = cvtpk(acc[mf][nf][2], acc[mf][nf][3]);
        int bofs = (dim * 256 + srcb * 2) ^ SW(dim);
        if (srcb < 124) { uint2 u = { lo, hi }; *(uint2*)(Ht + bofs) = u; }
        else            { *(unsigned*)(Ht + bofs) = lo; }   // src 124,125; 126/127 via GEMV
      }
    }
  }

  // ---- GEMV: user/item source rows (threads 0..511) ----
  if (tid < 512) {
    const int r2 = F_ + (tid >> 8);
    const int c2 = tid & 255;
    const float* er = (tid < 256) ? (utab + (size_t)userid[g] * 256)
                                  : (itab + (size_t)itemid[g] * 256);
    const uint4* wr = (const uint4*)(wct + (size_t)(1 + (tid >> 8)) * 65536 + (size_t)c2 * 256);
    const float4* e4 = (const float4*)er;
    float hv = 0.f;
#pragma unroll 4
    for (int j = 0; j < 32; ++j) {
      uint4 w8 = wr[j];
      float4 e0 = e4[2 * j], e1 = e4[2 * j + 1];
      const unsigned short* wp = (const unsigned short*)&w8;
      hv += e0.x * bf2f(wp[0]) + e0.y * bf2f(wp[1]) + e0.z * bf2f(wp[2]) + e0.w * bf2f(wp[3]);
      hv += e1.x * bf2f(wp[4]) + e1.y * bf2f(wp[5]) + e1.z * bf2f(wp[6]) + e1.w * bf2f(wp[7]);
    }
    float gps = hv * asl[c2];
    float gpd = hv * adl[c2];
#pragma unroll
    for (int d2 = 32; d2 >= 1; d2 >>= 1) { gps += __shfl_xor(gps, d2); gpd += __shfl_xor(gpd, d2); }
    if (lane == 0) {
      int h2 = wid & 3;
      EsT[h2 * 128 + r2] = __expf(gps);
      FsT[h2 * 128 + r2] = __expf(NEG_SLOPE * gps);
      EdT[h2 * 128 + r2] = __expf(gpd);
      FdT[h2 * 128 + r2] = __expf(NEG_SLOPE * gpd);
    }
    *(unsigned short*)(Ht + ((c2 * 256 + r2 * 2) ^ SW(c2))) = f2bf(hv);
  }
  __syncthreads();                                           // b1: M, hT, exp tables ready

  // ---- 4 head passes, barrier-free; A[d][s] = M[d][s] * max(Es[s]Ed[d], Fs[s]Fd[d]) ----
  float lp[4] = {};
  const int m2 = (wid & 7) * 16, n2 = (wid >> 3) * 32;
  const int drow = m2 + rl;

  for (int hd = 0; hd < 4; ++hd) {
    const float Edv = EdT[hd * 128 + drow];
    const float Fdv = FdT[hd * 128 + drow];
    float denp = 0.f;
    f32x4 acc2[2] = {};
#pragma unroll
    for (int ks = 0; ks < 4; ++ks) {
      uint2 m8 = *(const uint2*)(Mb + ((drow * 128 + ks * 32 + kg * 8) ^ SWB(drow)));
      f32x4 Es0 = *(const f32x4*)(&EsT[hd * 128 + ks * 32 + kg * 8]);
      f32x4 Es1 = *(const f32x4*)(&EsT[hd * 128 + ks * 32 + kg * 8 + 4]);
      f32x4 Fs0 = *(const f32x4*)(&FsT[hd * 128 + ks * 32 + kg * 8]);
      f32x4 Fs1 = *(const f32x4*)(&FsT[hd * 128 + ks * 32 + kg * 8 + 4]);
      float av[8];
#pragma unroll
      for (int j = 0; j < 8; ++j) {
        float mv = (float)(int)((j < 4 ? (m8.x >> (8 * j)) : (m8.y >> (8 * (j - 4)))) & 255u);
        float w = fmaxf(((j < 4) ? Es0[j] : Es1[j - 4]) * Edv,
                        ((j < 4) ? Fs0[j] : Fs1[j - 4]) * Fdv) * mv;
        av[j] = w;
        denp += w;
      }
      bfpack a2;
      a2.u[0] = cvtpk(av[0], av[1]); a2.u[1] = cvtpk(av[2], av[3]);
      a2.u[2] = cvtpk(av[4], av[5]); a2.u[3] = cvtpk(av[6], av[7]);
      bf16x8 b2[2];
#pragma unroll
      for (int nf = 0; nf < 2; ++nf) {
        int dim = hd * 64 + n2 + nf * 16 + rl;
        b2[nf] = *(const bf16x8*)(Ht + ((dim * 256 + ks * 64 + kg * 16) ^ SW(dim)));
      }
#pragma unroll
      for (int nf = 0; nf < 2; ++nf)
        acc2[nf] = __builtin_amdgcn_mfma_f32_16x16x32_bf16(a2.v, b2[nf], acc2[nf], 0, 0, 0);
    }
    denp += __shfl_xor(denp, 16);
    denp += __shfl_xor(denp, 32);
#pragma unroll
    for (int i = 0; i < 4; ++i) {
      float dni = __shfl(denp, kg * 4 + i);
      float rd = __builtin_amdgcn_rcpf(dni + 1e-16f);
#pragma unroll
      for (int nf = 0; nf < 2; ++nf) {
        float v = acc2[nf][i] * rd;
        v = (v > 0.f) ? v : (__expf(v) - 1.f);
        lp[i] += v * wo[hd * 64 + n2 + nf * 16 + rl];
      }
    }
  }

  // ---- readout reduce + direct store ----
#pragma unroll
  for (int i = 0; i < 4; ++i) {
    float v = lp[i];
#pragma unroll
    for (int d2 = 1; d2 < 16; d2 <<= 1) v += __shfl_xor(v, d2);
    if (rl == 0) lpf[(m2 + kg * 4 + i) * 2 + (wid >> 3)] = v;
  }
  __syncthreads();                                           // b2
  if (tid < F_) out[(size_t)g * F_ + tid] = lpf[tid * 2] + lpf[tid * 2 + 1] + bo;
}

extern "C" void kernel_launch(void* const* d_in, const int* in_sizes, int n_in,
                              void* d_out, int out_size, void* d_ws, size_t ws_size,
                              hipStream_t stream) {
  const int* fid      = (const int*)d_in[0];
  const int* userid   = (const int*)d_in[1];
  const int* itemid   = (const int*)d_in[2];
  const int* ei       = (const int*)d_in[3];
  const float* ftab   = (const float*)d_in[4];
  const float* utab   = (const float*)d_in[5];
  const float* itab   = (const float*)d_in[6];
  const float* Wf     = (const float*)d_in[7];
  const float* Wu     = (const float*)d_in[8];
  const float* Wi     = (const float*)d_in[9];
  const float* Wg     = (const float*)d_in[10];
  const float* a_src  = (const float*)d_in[11];
  const float* a_dst  = (const float*)d_in[12];
  const float* W_out  = (const float*)d_in[13];
  const float* b_out  = (const float*)d_in[14];
  float* out = (float*)d_out;

  unsigned short* ws_wct = (unsigned short*)d_ws;
  unsigned char*  ws_M   = (unsigned char*)d_ws + WS_M;

  hipLaunchKernelGGL(k0p, dim3(352), dim3(256), 0, stream, Wf, Wu, Wi, Wg, ei, ws_wct, ws_M);
  hipLaunchKernelGGL(k2f, dim3(256), dim3(1024), 0, stream,
                     fid, userid, itemid, ftab, utab, itab, ws_wct, ws_M,
                     a_src, a_dst, W_out, b_out, out);
}

// Round 17
// 53.286 us; speedup vs baseline: 3.0116x; 1.2438x over previous
//
#include <hip/hip_runtime.h>
#include <math.h>

// Problem constants
#define F_ 126
#define NPG 128              // nodes per graph
#define EPG 2048             // edges per graph
#define ET 524288            // total edges
#define NEG_SLOPE 0.2f

typedef short bf16x8 __attribute__((ext_vector_type(8)));
typedef float f32x4 __attribute__((ext_vector_type(4)));

__device__ __forceinline__ float bf2f(unsigned short u) {
  return __uint_as_float(((unsigned)u) << 16);
}
__device__ __forceinline__ unsigned short f2bf(float f) {
  unsigned x = __float_as_uint(f);
  unsigned r = x + 0x7fffu + ((x >> 16) & 1u);   // RNE
  return (unsigned short)(r >> 16);
}
// single-instruction packed f32x2 -> bf16x2 (RNE), gfx950
__device__ __forceinline__ unsigned cvtpk(float lo, float hi) {
  unsigned r;
  asm("v_cvt_pk_bf16_f32 %0, %1, %2" : "=v"(r) : "v"(lo), "v"(hi));
  return r;
}
union bfpack { unsigned u[4]; bf16x8 v; };

#define SW(r)  (((r) & 7) << 4)    // bf16-row swizzle (16B granule)
#define SWB(d) (((d) & 15) << 3)   // byte-matrix swizzle (8B granule)

// ws layout: [0,384K) wct bf16 [3][256][256];  [WS_M, +4MB) M u8 [256 g][16384] (SWB)
#define WS_M    393216

// ---------------- K0P: wct (coalesced) + M multiplicity build -----------------------------
__global__ __launch_bounds__(256) void k0p(
    const float* __restrict__ Wf, const float* __restrict__ Wu,
    const float* __restrict__ Wi, const float* __restrict__ Wg,
    const int* __restrict__ ei,
    unsigned short* __restrict__ wct, unsigned char* __restrict__ Mws) {
  const int blk = blockIdx.x;
  const int tid = threadIdx.x;
  if (blk < 96) {
    const int type = blk / 32;
    const int kc = blk % 32;
    const float* Wx = (type == 0) ? Wf : ((type == 1) ? Wu : Wi);
    __shared__ float Xs[8][256];
#pragma unroll
    for (int r = 0; r < 8; ++r) Xs[r][tid] = Wx[(kc * 8 + r) * 256 + tid];  // coalesced
    __syncthreads();
    float acc[8] = {};
#pragma unroll 16
    for (int j = 0; j < 256; ++j) {
      float wg = Wg[j * 256 + tid];                // coalesced across threads
#pragma unroll
      for (int r = 0; r < 8; ++r) acc[r] += Xs[r][j] * wg;
    }
#pragma unroll
    for (int r = 0; r < 8; ++r)
      wct[((size_t)type * 256 + tid) * 256 + kc * 8 + r] = f2bf(acc[r]);
  } else {
    // per-graph M build (byte-packed multiplicity, SWB-swizzled)
    const int g = blk - 96;
    __shared__ __align__(16) unsigned char Ml[16384];
    {
      uint4 z = { 0, 0, 0, 0 };
#pragma unroll
      for (int i = 0; i < 4; ++i) *(uint4*)(Ml + tid * 16 + i * 4096) = z;
    }
    int4 sa = *(const int4*)(ei + (size_t)g * EPG + tid * 8);
    int4 sb = *(const int4*)(ei + (size_t)g * EPG + tid * 8 + 4);
    int4 da = *(const int4*)(ei + (size_t)ET + (size_t)g * EPG + tid * 8);
    int4 db = *(const int4*)(ei + (size_t)ET + (size_t)g * EPG + tid * 8 + 4);
    __syncthreads();
    int ss[8] = { sa.x - g * NPG, sa.y - g * NPG, sa.z - g * NPG, sa.w - g * NPG,
                  sb.x - g * NPG, sb.y - g * NPG, sb.z - g * NPG, sb.w - g * NPG };
    int dd[8] = { da.x - g * NPG, da.y - g * NPG, da.z - g * NPG, da.w - g * NPG,
                  db.x - g * NPG, db.y - g * NPG, db.z - g * NPG, db.w - g * NPG };
#pragma unroll
    for (int j = 0; j < 8; ++j) {
      int bofs = (dd[j] * 128 + ss[j]) ^ SWB(dd[j]);
      atomicAdd((int*)(Ml + (bofs & ~3)), 1 << ((bofs & 3) * 8));
    }
    __syncthreads();
    unsigned char* Mdst = Mws + (size_t)g * 16384;
#pragma unroll
    for (int i = 0; i < 4; ++i)
      *(uint4*)(Mdst + tid * 16 + i * 4096) = *(const uint4*)(Ml + tid * 16 + i * 4096);
  }
}

// ---------------- K2F: fused per-graph kernel; A+B LDS-staged GEMM1 -----------------------
// LDS: [0,64K) A bf16 [128 rows][512B] (XOR-swz) -> hT bf16 [256][256B] after GEMM1
//      [64K,128K) B dbuf 2x[256 dim][128B] | [128K,+16K) M u8 | tables | small
#define OFF_A    0
#define OFF_HT   0
#define OFF_B    65536
#define OFF_M    131072
#define OFF_ES   147456
#define OFF_FS   149504
#define OFF_ED   151552
#define OFF_FD   153600
#define OFF_ASL  155648
#define OFF_ADL  156672
#define OFF_WO   157696
#define OFF_LP   158720
#define LDS_SZ   159744

__global__ __launch_bounds__(1024, 1) void k2f(
    const int* __restrict__ fid, const int* __restrict__ userid, const int* __restrict__ itemid,
    const float* __restrict__ ftab, const float* __restrict__ utab, const float* __restrict__ itab,
    const unsigned short* __restrict__ wct, const unsigned char* __restrict__ Mws,
    const float* __restrict__ a_src, const float* __restrict__ a_dst,
    const float* __restrict__ W_out, const float* __restrict__ b_out,
    float* __restrict__ out) {
  __shared__ __align__(16) char smem[LDS_SZ];
  const int g = blockIdx.x;
  const int tid = threadIdx.x;
  const int lane = tid & 63;
  const int wid = tid >> 6;          // 0..15
  const int rl = lane & 15;
  const int kg = lane >> 4;

  char* Ht = smem + OFF_HT;
  char* Mb = smem + OFF_M;
  float* EsT = (float*)(smem + OFF_ES);   // [hd*128 + node]
  float* FsT = (float*)(smem + OFF_FS);
  float* EdT = (float*)(smem + OFF_ED);
  float* FdT = (float*)(smem + OFF_FD);
  float* asl = (float*)(smem + OFF_ASL);
  float* adl = (float*)(smem + OFF_ADL);
  float* wo  = (float*)(smem + OFF_WO);
  float* lpf = (float*)(smem + OFF_LP);

  // M: global -> LDS (dedicated region)
  *(uint4*)(Mb + tid * 16) = *(const uint4*)(Mws + (size_t)g * 16384 + tid * 16);

  if (tid < 256)      { asl[tid] = a_src[tid]; wo[tid] = W_out[tid]; }
  else if (tid < 512) { adl[tid - 256] = a_dst[tid - 256]; }
  const float bo = b_out[0];

  // B-stage thread mapping: dim bd = tid>>2, quarter bq = tid&3 (32B per thread per chunk)
  const int bd = tid >> 2, bq = tid & 3;
#define BSTAGE_LOAD(c, r0, r1)                                                   \
  r0 = *(const uint4*)(wct + (size_t)bd * 256 + (c) * 64 + bq * 16);             \
  r1 = *(const uint4*)(wct + (size_t)bd * 256 + (c) * 64 + bq * 16 + 8);
#define BSTAGE_WRITE(c, r0, r1)                                                  \
  { char* Bw = smem + OFF_B + ((c) & 1) * 32768;                                 \
    *(uint4*)(Bw + bd * 128 + ((bq * 32) ^ SW(bd))) = r0;                        \
    *(uint4*)(Bw + bd * 128 + ((bq * 32 + 16) ^ SW(bd))) = r1; }

  // stage B chunk 0
  {
    uint4 s0, s1;
    BSTAGE_LOAD(0, s0, s1)
    BSTAGE_WRITE(0, s0, s1)
  }

  // ---- A-stage: gather embed rows -> bf16 LDS [128][512B], XOR-swizzled ----
  {
    const int r = tid >> 3, q = tid & 7;
    const float* srcrow;
    if (r < F_)       srcrow = ftab + (size_t)fid[g * F_ + r] * 256;
    else if (r == F_) srcrow = utab + (size_t)userid[g] * 256;   // raw user emb (row 126)
    else              srcrow = itab + (size_t)itemid[g] * 256;   // raw item emb (row 127)
    char* Ab = smem + OFF_A;
#pragma unroll
    for (int j = 0; j < 8; ++j) {
      float4 v = *(const float4*)(srcrow + q * 4 + j * 32);
      uint2 st;
      st.x = cvtpk(v.x, v.y);
      st.y = cvtpk(v.z, v.w);
      *(uint2*)(Ab + r * 512 + ((q * 8 + j * 64) ^ SW(r))) = st;
    }
  }
  __syncthreads();                                           // b0: A + B0 + M staged

  // ---- GEMM1: h = emb @ Wc(type0); A,B from LDS; B dbuf pipelined ----
  const int mh = wid & 3, nq = wid >> 2;    // rows mh*32..+32, dims nq*64..+64 (head nq)
  f32x4 acc[2][4] = {};

#define G1ROUND(buf, ks)                                                                   \
  {                                                                                        \
    const char* Ab = smem + OFF_A;                                                         \
    const char* Bc = smem + OFF_B + (buf) * 32768;                                         \
    bf16x8 af[2], bfv[4];                                                                  \
    _Pragma("unroll")                                                                      \
    for (int mf = 0; mf < 2; ++mf) {                                                       \
      int row = mh * 32 + mf * 16 + rl;                                                    \
      af[mf] = *(const bf16x8*)(Ab + row * 512 + (((ks) * 64 + kg * 16) ^ SW(row)));       \
    }                                                                                      \
    _Pragma("unroll")                                                                      \
    for (int nf = 0; nf < 4; ++nf) {                                                       \
      int d = nq * 64 + nf * 16 + rl;                                                      \
      bfv[nf] = *(const bf16x8*)(Bc + d * 128 + ((((ks) & 1) * 64 + kg * 16) ^ SW(d)));    \
    }                                                                                      \
    _Pragma("unroll")                                                                      \
    for (int mf = 0; mf < 2; ++mf)                                                         \
      _Pragma("unroll")                                                                    \
      for (int nf = 0; nf < 4; ++nf)                                                       \
        acc[mf][nf] = __builtin_amdgcn_mfma_f32_16x16x32_bf16(af[mf], bfv[nf], acc[mf][nf], 0, 0, 0); \
  }

  {
    uint4 s0, s1;
    BSTAGE_LOAD(1, s0, s1)
    G1ROUND(0, 0) G1ROUND(0, 1)
    BSTAGE_WRITE(1, s0, s1)
  }
  __syncthreads();
  {
    uint4 s0, s1;
    BSTAGE_LOAD(2, s0, s1)
    G1ROUND(1, 2) G1ROUND(1, 3)
    BSTAGE_WRITE(2, s0, s1)
  }
  __syncthreads();
  {
    uint4 s0, s1;
    BSTAGE_LOAD(3, s0, s1)
    G1ROUND(0, 4) G1ROUND(0, 5)
    BSTAGE_WRITE(3, s0, s1)
  }
  __syncthreads();
  G1ROUND(1, 6) G1ROUND(1, 7)

  // ---- exp tables from f32 acc (head = nq; rows < 126) ----
  {
    float asv[4], adv[4];
#pragma unroll
    for (int nf = 0; nf < 4; ++nf) {
      asv[nf] = asl[nq * 64 + nf * 16 + rl];
      adv[nf] = adl[nq * 64 + nf * 16 + rl];
    }
#pragma unroll
    for (int mf = 0; mf < 2; ++mf) {
#pragma unroll
      for (int i = 0; i < 4; ++i) {
        float ps = 0.f, pd = 0.f;
#pragma unroll
        for (int nf = 0; nf < 4; ++nf) { float v = acc[mf][nf][i]; ps += v * asv[nf]; pd += v * adv[nf]; }
#pragma unroll
        for (int d2 = 1; d2 < 16; d2 <<= 1) { ps += __shfl_xor(ps, d2); pd += __shfl_xor(pd, d2); }
        int row = mh * 32 + mf * 16 + kg * 4 + i;
        if (rl == 0 && row < F_) {
          EsT[nq * 128 + row] = __expf(ps);
          FsT[nq * 128 + row] = __expf(NEG_SLOPE * ps);
          EdT[nq * 128 + row] = __expf(pd);
          FdT[nq * 128 + row] = __expf(NEG_SLOPE * pd);
        }
      }
    }
  }

  // ---- GEMV-via-MFMA: rows 126 (user, type1) / 127 (item, type2), waves 8..15 ----
  // wave w = wid-8: type t = 1+(w&1), head dg = w>>1. A = A-LDS rows 112..127.
  float ghv0 = 0.f, ghv1 = 0.f, ghv2 = 0.f, ghv3 = 0.f;
  int gr2 = 126, gdg = 0, gt = 1;
  if (wid >= 8) {
    const int w = wid - 8;
    gt = 1 + (w & 1);
    gdg = w >> 1;
    gr2 = 125 + gt;
    const unsigned short* bgp[4];
#pragma unroll
    for (int nf = 0; nf < 4; ++nf)
      bgp[nf] = wct + (size_t)(gt * 256 + gdg * 64 + nf * 16 + rl) * 256;
    f32x4 acc2[4] = {};
    const char* Ab = smem + OFF_A;
#pragma unroll
    for (int ks = 0; ks < 8; ++ks) {
      int row = 112 + rl;
      bf16x8 af = *(const bf16x8*)(Ab + row * 512 + ((ks * 64 + kg * 16) ^ SW(row)));
      bf16x8 bfv[4];
#pragma unroll
      for (int nf = 0; nf < 4; ++nf)
        bfv[nf] = *(const bf16x8*)(bgp[nf] + ks * 32 + kg * 8);
#pragma unroll
      for (int nf = 0; nf < 4; ++nf)
        acc2[nf] = __builtin_amdgcn_mfma_f32_16x16x32_bf16(af, bfv[nf], acc2[nf], 0, 0, 0);
    }
    // extract C rows 126/127: kg==3, i = 2 (t==1) or 3 (t==2)
    ghv0 = (gt == 1) ? acc2[0][2] : acc2[0][3];
    ghv1 = (gt == 1) ? acc2[1][2] : acc2[1][3];
    ghv2 = (gt == 1) ? acc2[2][2] : acc2[2][3];
    ghv3 = (gt == 1) ? acc2[3][2] : acc2[3][3];
    // exp tables for (head gdg, row gr2): reduce over the kg==3 16-lane group
    float ps = ghv0 * asl[gdg * 64 + rl] + ghv1 * asl[gdg * 64 + 16 + rl]
             + ghv2 * asl[gdg * 64 + 32 + rl] + ghv3 * asl[gdg * 64 + 48 + rl];
    float pd = ghv0 * adl[gdg * 64 + rl] + ghv1 * adl[gdg * 64 + 16 + rl]
             + ghv2 * adl[gdg * 64 + 32 + rl] + ghv3 * adl[gdg * 64 + 48 + rl];
#pragma unroll
    for (int d2 = 1; d2 < 16; d2 <<= 1) { ps += __shfl_xor(ps, d2); pd += __shfl_xor(pd, d2); }
    if (kg == 3 && rl == 0) {
      EsT[gdg * 128 + gr2] = __expf(ps);
      FsT[gdg * 128 + gr2] = __expf(NEG_SLOPE * ps);
      EdT[gdg * 128 + gr2] = __expf(pd);
      FdT[gdg * 128 + gr2] = __expf(NEG_SLOPE * pd);
    }
  }
  __syncthreads();                         // all A-LDS reads done -> region reusable for hT

  // ---- transpose-write hT[dim][src] into freed A region ----
  {
#pragma unroll
    for (int mf = 0; mf < 2; ++mf) {
      int srcb = mh * 32 + mf * 16 + kg * 4;
#pragma unroll
      for (int nf = 0; nf < 4; ++nf) {
        int dim = nq * 64 + nf * 16 + rl;
        unsigned lo = cvtpk(acc[mf][nf][0], acc[mf][nf][1]);
        unsigned hi = cvtpk(acc[mf][nf][2], acc[mf][nf][3]);
        int bofs = (dim * 256 + srcb * 2) ^ SW(dim);
        if (srcb < 124) { uint2 u = { lo, hi }; *(uint2*)(Ht + bofs) = u; }
        else            { *(unsigned*)(Ht + bofs) = lo; }   // src 124,125
      }
    }
    // src 126/127 from GEMV-MFMA (waves 8..15, kg==3 lanes hold 4 dims each)
    if (wid >= 8 && kg == 3) {
      int d0 = gdg * 64 + rl;
      *(unsigned short*)(Ht + ((d0 * 256 + gr2 * 2) ^ SW(d0))) = f2bf(ghv0);
      int d1 = d0 + 16;
      *(unsigned short*)(Ht + ((d1 * 256 + gr2 * 2) ^ SW(d1))) = f2bf(ghv1);
      int d2 = d0 + 32;
      *(unsigned short*)(Ht + ((d2 * 256 + gr2 * 2) ^ SW(d2))) = f2bf(ghv2);
      int d3 = d0 + 48;
      *(unsigned short*)(Ht + ((d3 * 256 + gr2 * 2) ^ SW(d3))) = f2bf(ghv3);
    }
  }
  __syncthreads();                                           // b1: M, hT, exp tables ready

  // ---- 4 head passes, barrier-free; A[d][s] = M[d][s] * max(Es[s]Ed[d], Fs[s]Fd[d]) ----
  float lp[4] = {};
  const int m2 = (wid & 7) * 16, n2 = (wid >> 3) * 32;
  const int drow = m2 + rl;

  for (int hd = 0; hd < 4; ++hd) {
    const float Edv = EdT[hd * 128 + drow];
    const float Fdv = FdT[hd * 128 + drow];
    float denp = 0.f;
    f32x4 acc2[2] = {};
#pragma unroll
    for (int ks = 0; ks < 4; ++ks) {
      uint2 m8 = *(const uint2*)(Mb + ((drow * 128 + ks * 32 + kg * 8) ^ SWB(drow)));
      f32x4 Es0 = *(const f32x4*)(&EsT[hd * 128 + ks * 32 + kg * 8]);
      f32x4 Es1 = *(const f32x4*)(&EsT[hd * 128 + ks * 32 + kg * 8 + 4]);
      f32x4 Fs0 = *(const f32x4*)(&FsT[hd * 128 + ks * 32 + kg * 8]);
      f32x4 Fs1 = *(const f32x4*)(&FsT[hd * 128 + ks * 32 + kg * 8 + 4]);
      float av[8];
#pragma unroll
      for (int j = 0; j < 8; ++j) {
        float mv = (float)(int)((j < 4 ? (m8.x >> (8 * j)) : (m8.y >> (8 * (j - 4)))) & 255u);
        float w = fmaxf(((j < 4) ? Es0[j] : Es1[j - 4]) * Edv,
                        ((j < 4) ? Fs0[j] : Fs1[j - 4]) * Fdv) * mv;
        av[j] = w;
        denp += w;
      }
      bfpack a2;
      a2.u[0] = cvtpk(av[0], av[1]); a2.u[1] = cvtpk(av[2], av[3]);
      a2.u[2] = cvtpk(av[4], av[5]); a2.u[3] = cvtpk(av[6], av[7]);
      bf16x8 b2[2];
#pragma unroll
      for (int nf = 0; nf < 2; ++nf) {
        int dim = hd * 64 + n2 + nf * 16 + rl;
        b2[nf] = *(const bf16x8*)(Ht + ((dim * 256 + ks * 64 + kg * 16) ^ SW(dim)));
      }
#pragma unroll
      for (int nf = 0; nf < 2; ++nf)
        acc2[nf] = __builtin_amdgcn_mfma_f32_16x16x32_bf16(a2.v, b2[nf], acc2[nf], 0, 0, 0);
    }
    denp += __shfl_xor(denp, 16);
    denp += __shfl_xor(denp, 32);
#pragma unroll
    for (int i = 0; i < 4; ++i) {
      float dni = __shfl(denp, kg * 4 + i);
      float rd = __builtin_amdgcn_rcpf(dni + 1e-16f);
#pragma unroll
      for (int nf = 0; nf < 2; ++nf) {
        float v = acc2[nf][i] * rd;
        v = (v > 0.f) ? v : (__expf(v) - 1.f);
        lp[i] += v * wo[hd * 64 + n2 + nf * 16 + rl];
      }
    }
  }

  // ---- readout reduce + direct store ----
#pragma unroll
  for (int i = 0; i < 4; ++i) {
    float v = lp[i];
#pragma unroll
    for (int d2 = 1; d2 < 16; d2 <<= 1) v += __shfl_xor(v, d2);
    if (rl == 0) lpf[(m2 + kg * 4 + i) * 2 + (wid >> 3)] = v;
  }
  __syncthreads();                                           // b2
  if (tid < F_) out[(size_t)g * F_ + tid] = lpf[tid * 2] + lpf[tid * 2 + 1] + bo;
}

extern "C" void kernel_launch(void* const* d_in, const int* in_sizes, int n_in,
                              void* d_out, int out_size, void* d_ws, size_t ws_size,
                              hipStream_t stream) {
  const int* fid      = (const int*)d_in[0];
  const int* userid   = (const int*)d_in[1];
  const int* itemid   = (const int*)d_in[2];
  const int* ei       = (const int*)d_in[3];
  const float* ftab   = (const float*)d_in[4];
  const float* utab   = (const float*)d_in[5];
  const float* itab   = (const float*)d_in[6];
  const float* Wf     = (const float*)d_in[7];
  const float* Wu     = (const float*)d_in[8];
  const float* Wi     = (const float*)d_in[9];
  const float* Wg     = (const float*)d_in[10];
  const float* a_src  = (const float*)d_in[11];
  const float* a_dst  = (const float*)d_in[12];
  const float* W_out  = (const float*)d_in[13];
  const float* b_out  = (const float*)d_in[14];
  float* out = (float*)d_out;

  unsigned short* ws_wct = (unsigned short*)d_ws;
  unsigned char*  ws_M   = (unsigned char*)d_ws + WS_M;

  hipLaunchKernelGGL(k0p, dim3(352), dim3(256), 0, stream, Wf, Wu, Wi, Wg, ei, ws_wct, ws_M);
  hipLaunchKernelGGL(k2f, dim3(256), dim3(1024), 0, stream,
                     fid, userid, itemid, ftab, utab, itab, ws_wct, ws_M,
                     a_src, a_dst, W_out, b_out, out);
}